// Round 4
// baseline (406.422 us; speedup 1.0000x reference)
//
#include <hip/hip_runtime.h>
#include <stdint.h>

// Output layout (float32 elements within d_out):
//   q_out : [8][1024][64][64]  at offset 0          (33,554,432)
//   code  : [8][4][64][64]     at offset 33,554,432 (131,072)  -- stored as float
//   logit : [8][1024][64][64]  at offset 33,685,504 (33,554,432)
#define CODE_OFF  33554432u
#define LOGIT_OFF 33685504u

typedef __attribute__((address_space(1))) const void g_void;
typedef __attribute__((address_space(3))) void l_void;

__device__ __forceinline__ uint32_t rotl32(uint32_t x, int r) {
  return (x << r) | (x >> (32 - r));
}

// Partitionable threefry (JAX >= 0.4.36 default): counter words (0, flat_idx),
// key (0,42), 20 rounds, draw = o0 ^ o1. Verified bit-exact in round 2.
__device__ __forceinline__ uint32_t tf32_part(uint32_t i) {
  const uint32_t ks1 = 42u;
  const uint32_t ks2 = 0x1BD11BDAu ^ 42u;  // ks0 = 0
  uint32_t x0 = 0u;
  uint32_t x1 = i + ks1;
#define R4(a,b,c,d) \
  x0 += x1; x1 = rotl32(x1,(a)); x1 ^= x0; \
  x0 += x1; x1 = rotl32(x1,(b)); x1 ^= x0; \
  x0 += x1; x1 = rotl32(x1,(c)); x1 ^= x0; \
  x0 += x1; x1 = rotl32(x1,(d)); x1 ^= x0;
  R4(13,15,26,6)   x0 += ks1; x1 += ks2 + 1u;
  R4(17,29,16,24)  x0 += ks2; x1 += 2u;
  R4(13,15,26,6)               x1 += ks1 + 3u;
  R4(17,29,16,24)  x0 += ks1; x1 += ks2 + 4u;
  R4(13,15,26,6)   x0 += ks2; x1 += 5u;
#undef R4
  return x0 ^ x1;
}

__device__ __forceinline__ float bits_to_gumbel(uint32_t bits) {
  uint32_t fb = (bits >> 9) | 0x3f800000u;
  float f = __uint_as_float(fb) - 1.0f;
  float u = (f > 0.0f) ? f : 1.17549435e-38f;
  return -logf(-logf(u));
}

// Grid 8192, block 256 (4 waves). bid = nm*512 + half*256 + tile.
// plane = nm + 16*half = (n + 4*half)*4 + m; hw0 = tile*16.
// Thread: px = tid&3 -> 4 consecutive hw positions hw0 + 4*px + p;
//         ty = tid>>2 in [0,64): 4 k's, k = ty*4 + jd.
// K-loop: 8 chunks of 8 channels; w double-buffered (1 barrier/chunk);
// 2 threefry+gumbel draws per chunk (fills stalls).
// LDS 20 KB (x 4 KB + w 16 KB) -> 8 blocks/CU target; 16 accs -> low VGPR.
__global__ __launch_bounds__(256, 4)
void mcq_kernel(const float* __restrict__ x, const float* __restrict__ w,
                float* __restrict__ out) {
  __shared__ __align__(16) float x_lds[1024];  // [c(64)][pos(16)]
  __shared__ __align__(16) float w_lds[4096];  // 2 x [cc(8)][k(256)] buffers

  const int tid = threadIdx.x;
  const int px = tid & 3;
  const int ty = tid >> 2;
  const int bid = blockIdx.x;
  const int nm = bid >> 9;          // 512 consecutive blocks share the w row
  const int half = (bid >> 8) & 1;
  const int tile = bid & 255;
  const int hw0 = tile * 16;
  const int m = nm & 3;
  const int plane = nm + 16 * half; // (n + 4*half)*4 + m

  float* q_out = out;
  float* code_out = out + CODE_OFF;
  float* logit_out = out + LOGIT_OFF;

  // ---- stage x via global_load_lds (width 16); layout [c][pos] ----
  {
    // x offset for (n', m*64 + c, hw): ((n'*256 + m*64) + c)*4096 = plane*64*4096 + c*4096
    const float* xbase = x + (size_t)plane * 262144 + hw0;
    const float* src = xbase + (size_t)(tid >> 2) * 4096 + (tid & 3) * 4;
    // wave-uniform LDS base; HW scatters lane*16 -> linear [c][16] layout
    float* dst = x_lds + ((tid & ~63) << 2);
    __builtin_amdgcn_global_load_lds((g_void*)src, (l_void*)dst, 16, 0, 0);
  }

  const float* wrow = w + (size_t)m * 256 * 64;  // w[m][k][c], c contiguous
  float4 wr0, wr1;
  {  // chunk 0 of w (8 channels) into regs, then transposed to LDS buf0
    const float* wk = wrow + tid * 64;
    wr0 = *(const float4*)(wk + 0);
    wr1 = *(const float4*)(wk + 4);
    w_lds[0 * 256 + tid] = wr0.x; w_lds[1 * 256 + tid] = wr0.y;
    w_lds[2 * 256 + tid] = wr0.z; w_lds[3 * 256 + tid] = wr0.w;
    w_lds[4 * 256 + tid] = wr1.x; w_lds[5 * 256 + tid] = wr1.y;
    w_lds[6 * 256 + tid] = wr1.z; w_lds[7 * 256 + tid] = wr1.w;
  }
  __syncthreads();  // drains x's lds-loads (vmcnt) + w writes

  // acc[p][jd]: p = position offset, jd = k slot. gmb same shape.
  float acc[4][4], gmb[4][4];
#pragma unroll
  for (int p = 0; p < 4; ++p)
#pragma unroll
    for (int jd = 0; jd < 4; ++jd) acc[p][jd] = 0.0f;

  // flat draw index = (plane*4096 + hw)*256 + k, hw = hw0 + 4*px + p
  const uint32_t base0 = ((uint32_t)(plane * 4096 + hw0 + 4 * px)) << 8;

#pragma unroll
  for (int chunk = 0; chunk < 8; ++chunk) {
    if (chunk < 7) {  // prefetch next w chunk into regs (retires under compute)
      const float* wk = wrow + tid * 64 + (chunk + 1) * 8;
      wr0 = *(const float4*)(wk + 0);
      wr1 = *(const float4*)(wk + 4);
    }
    {  // 2 threefry+gumbel draws per chunk (independent ALU: fills stalls)
#pragma unroll
      for (int i = 0; i < 2; ++i) {
        const int d = chunk * 2 + i;         // compile-time after unroll
        const int p = d >> 2, jd = d & 3;
        const uint32_t k = (uint32_t)(ty * 4 + jd);
        gmb[p][jd] = bits_to_gumbel(tf32_part(base0 + (uint32_t)p * 256u + k));
      }
    }
    const int rb = (chunk & 1) << 11;  // read buffer base
#pragma unroll
    for (int cc = 0; cc < 8; ++cc) {
      int c = chunk * 8 + cc;
      float4 xv = *(const float4*)&x_lds[c * 16 + px * 4];
      float4 wv = *(const float4*)&w_lds[rb + cc * 256 + ty * 4];
      float xa[4] = {xv.x, xv.y, xv.z, xv.w};
      float wa[4] = {wv.x, wv.y, wv.z, wv.w};
#pragma unroll
      for (int p = 0; p < 4; ++p)
#pragma unroll
        for (int jd = 0; jd < 4; ++jd) acc[p][jd] += xa[p] * wa[jd];
    }
    if (chunk < 7) {
      // write next chunk into the other buffer; its previous readers finished
      // before the barrier that ended chunk-1. One barrier per chunk total.
      const int wb = ((chunk + 1) & 1) << 11;
      w_lds[wb + 0 * 256 + tid] = wr0.x; w_lds[wb + 1 * 256 + tid] = wr0.y;
      w_lds[wb + 2 * 256 + tid] = wr0.z; w_lds[wb + 3 * 256 + tid] = wr0.w;
      w_lds[wb + 4 * 256 + tid] = wr1.x; w_lds[wb + 5 * 256 + tid] = wr1.y;
      w_lds[wb + 6 * 256 + tid] = wr1.z; w_lds[wb + 7 * 256 + tid] = wr1.w;
      __syncthreads();
    }
  }

  // ---- epilogue: float4 logit stores + argmax (gumbels already in regs) ----
  float best[4]; int ib[4];
#pragma unroll
  for (int p = 0; p < 4; ++p) { best[p] = -3.4e38f; ib[p] = 0; }
  const size_t row_off = (size_t)hw0 + 4 * px;
#pragma unroll
  for (int jd = 0; jd < 4; ++jd) {
    int k = ty * 4 + jd;
    size_t off = ((size_t)(plane * 256 + k)) * 4096 + row_off;
    *(float4*)(logit_out + off) =
        make_float4(acc[0][jd], acc[1][jd], acc[2][jd], acc[3][jd]);
#pragma unroll
    for (int p = 0; p < 4; ++p) {
      float v = gmb[p][jd] + acc[p][jd];
      // jd ascending => k ascending per thread; '>' keeps smallest k on ties
      if (v > best[p]) { best[p] = v; ib[p] = k; }
    }
  }

  // ---- cross-thread argmax reduction over the 64 k-owners (ty) ----
  // Stage 0: all threads write [16 slots][65] val+idx into w_lds.
  __syncthreads();  // all compute reads of x_lds/w_lds done; reuse them
  float* red_val = w_lds;                 // [16][65] -> 1040 floats
  int* red_idx = (int*)(w_lds + 1056);    // [16][65]
#pragma unroll
  for (int p = 0; p < 4; ++p) {
    int slot = px * 4 + p;
    red_val[slot * 65 + ty] = best[p];
    red_idx[slot * 65 + ty] = ib[p];
  }
  __syncthreads();
  // Stage 1: 64 threads, each reduces 16 entries of one slot-quarter.
  float* pv = w_lds + 2112;               // [16][4]
  int* pi = (int*)(w_lds + 2176);         // [16][4]
  if (tid < 64) {
    int slot = tid >> 2, q = tid & 3;
    float bv = -3.4e38f; int bi = 0x7fffffff;
#pragma unroll
    for (int t = 0; t < 16; ++t) {
      float v = red_val[slot * 65 + q * 16 + t];
      int ix = red_idx[slot * 65 + q * 16 + t];
      if (v > bv || (v == bv && ix < bi)) { bv = v; bi = ix; }  // tie -> smallest k
    }
    pv[slot * 4 + q] = bv; pi[slot * 4 + q] = bi;
  }
  __syncthreads();
  // Stage 2: 16 threads finalize (q ascending keeps smallest-k tie rule).
  int* idx_final = (int*)x_lds;  // 16 ints; x_lds no longer needed
  if (tid < 16) {
    float bv = -3.4e38f; int bi = 0x7fffffff;
#pragma unroll
    for (int q = 0; q < 4; ++q) {
      float v = pv[tid * 4 + q]; int ix = pi[tid * 4 + q];
      if (v > bv || (v == bv && ix < bi)) { bv = v; bi = ix; }
    }
    idx_final[tid] = bi;
    code_out[(size_t)plane * 4096 + hw0 + tid] = (float)bi;
  }
  __syncthreads();

  // ---- one-hot q_out (race-free: every k written by its owner thread) ----
  const int f0 = idx_final[px * 4 + 0];
  const int f1 = idx_final[px * 4 + 1];
  const int f2 = idx_final[px * 4 + 2];
  const int f3 = idx_final[px * 4 + 3];
#pragma unroll
  for (int jd = 0; jd < 4; ++jd) {
    int k = ty * 4 + jd;
    size_t off = ((size_t)(plane * 256 + k)) * 4096 + row_off;
    *(float4*)(q_out + off) = make_float4(k == f0 ? 1.0f : 0.0f, k == f1 ? 1.0f : 0.0f,
                                          k == f2 ? 1.0f : 0.0f, k == f3 ? 1.0f : 0.0f);
  }
}

extern "C" void kernel_launch(void* const* d_in, const int* in_sizes, int n_in,
                              void* d_out, int out_size, void* d_ws, size_t ws_size,
                              hipStream_t stream) {
  const float* x = (const float*)d_in[0];  // [8][256][64][64] fp32
  const float* w = (const float*)d_in[1];  // [4][256][64] fp32
  float* out = (float*)d_out;
  mcq_kernel<<<dim3(8192), dim3(256), 0, stream>>>(x, w, out);
}